// Round 1
// baseline (108.967 us; speedup 1.0000x reference)
//
#include <hip/hip_runtime.h>
#include <hip/hip_bf16.h>
#include <math.h>

// Chamfer 2D: B=8 batches, N=4096 points per set, fp32.
// d2(x,y) = |x|^2 + |y|^2 - 2 x.y ; min over db of (s_j - 2 x.y_j) computed
// with 3 VALU ops/pair (2 fma + 1 min); |x|^2 and sqrt applied in stage 2.

#define B 8
#define N 4096
#define BLOCK 256
#define TX 8            // queries per thread
#define NI 2            // query tiles: NI * BLOCK * TX = 4096

// partial layout: [c][dir][n][i]  (c = j-chunk index)
__global__ __launch_bounds__(BLOCK) void chamfer_stage1(
    const float2* __restrict__ P1, const float2* __restrict__ P2,
    float* __restrict__ partial, int nj, int jc) {
  extern __shared__ float4 yb[];   // jc entries: {-2*y0, -2*y1, |y|^2, 0}

  int b = blockIdx.x;
  int c = b % nj; b /= nj;
  int itile = b % NI; b /= NI;
  int n = b % B;
  int dir = b / B;

  const float2* __restrict__ Q = dir ? P2 : P1;  // queries
  const float2* __restrict__ D = dir ? P1 : P2;  // database

  // stage database chunk into LDS, pre-transformed
  const float2* dbase = D + n * N + c * jc;
  for (int t = threadIdx.x; t < jc; t += BLOCK) {
    float2 p = dbase[t];
    yb[t] = make_float4(-2.0f * p.x, -2.0f * p.y,
                        fmaf(p.x, p.x, p.y * p.y), 0.0f);
  }
  __syncthreads();

  // load TX queries into registers (coalesced)
  float qx[TX], qy[TX], m[TX];
  const float2* qbase = Q + n * N + itile * (BLOCK * TX) + threadIdx.x;
#pragma unroll
  for (int k = 0; k < TX; ++k) {
    float2 q = qbase[k * BLOCK];
    qx[k] = q.x; qy[k] = q.y;
    m[k] = INFINITY;
  }

  // main loop: wave-uniform LDS broadcast of db point, 3 ops per pair
#pragma unroll 4
  for (int j = 0; j < jc; ++j) {
    float4 y = yb[j];
#pragma unroll
    for (int k = 0; k < TX; ++k) {
      float t = fmaf(qx[k], y.x, fmaf(qy[k], y.y, y.z));
      m[k] = fminf(m[k], t);
    }
  }

  float* dst = partial + (((size_t)c * 2 + dir) * B + n) * N
             + itile * (BLOCK * TX) + threadIdx.x;
#pragma unroll
  for (int k = 0; k < TX; ++k) dst[k * BLOCK] = m[k];
}

__global__ __launch_bounds__(BLOCK) void chamfer_stage2(
    const float2* __restrict__ P1, const float2* __restrict__ P2,
    const float* __restrict__ partial, float* __restrict__ out, int nj) {
  int n = blockIdx.x;
  float sum = 0.0f;

  for (int dir = 0; dir < 2; ++dir) {
    const float2* __restrict__ Q = dir ? P2 : P1;
    for (int i = threadIdx.x; i < N; i += BLOCK) {
      float m = INFINITY;
      for (int c = 0; c < nj; ++c)
        m = fminf(m, partial[(((size_t)c * 2 + dir) * B + n) * N + i]);
      float2 q = Q[n * N + i];
      float d2 = m + fmaf(q.x, q.x, q.y * q.y);
      sum += sqrtf(fmaxf(d2, 0.0f));
    }
  }

  __shared__ float red[BLOCK];
  red[threadIdx.x] = sum;
  __syncthreads();
  for (int s = BLOCK / 2; s > 0; s >>= 1) {
    if (threadIdx.x < s) red[threadIdx.x] += red[threadIdx.x + s];
    __syncthreads();
  }
  if (threadIdx.x == 0) out[n] = red[0] * (0.5f / (float)N);
}

extern "C" void kernel_launch(void* const* d_in, const int* in_sizes, int n_in,
                              void* d_out, int out_size, void* d_ws, size_t ws_size,
                              hipStream_t stream) {
  const float2* P1 = (const float2*)d_in[0];
  const float2* P2 = (const float2*)d_in[1];
  float* out = (float*)d_out;
  float* partial = (float*)d_ws;

  // pick j-split so partials fit in workspace: nj*2*B*N*4 bytes
  int nj = 16;
  while (nj > 1 && (size_t)nj * 2 * B * N * sizeof(float) > ws_size) nj >>= 1;
  int jc = N / nj;

  dim3 grid(2 * B * NI * nj);
  chamfer_stage1<<<grid, BLOCK, jc * sizeof(float4), stream>>>(P1, P2, partial, nj, jc);
  chamfer_stage2<<<B, BLOCK, 0, stream>>>(P1, P2, partial, out, nj);
}

// Round 2
// 30.051 us; speedup vs baseline: 3.6261x; 3.6261x over previous
//
#include <hip/hip_runtime.h>
#include <hip/hip_bf16.h>
#include <math.h>

// Chamfer 2D: B=8 batches, N=4096 points per set, fp32.
// d2(x,y) = |x|^2 + |y|^2 - 2 x.y ; min over db of (s_j - 2 x.y_j) computed
// with 3 VALU ops/pair (2 fma + 1 min); |x|^2 and sqrt applied in stage 2.

#define B 8
#define N 4096
#define BLOCK 256
#define TX 8            // queries per thread (stage1)
#define NI 2            // query tiles: NI * BLOCK * TX = 4096
#define NT 16           // i-tiles in stage2: NT * BLOCK = 4096

// partial layout: [c][dir][n][i]  (c = j-chunk index)
__global__ __launch_bounds__(BLOCK) void chamfer_stage1(
    const float2* __restrict__ P1, const float2* __restrict__ P2,
    float* __restrict__ partial, int nj, int jc) {
  extern __shared__ float4 yb[];   // jc entries: {-2*y0, -2*y1, |y|^2, 0}

  int b = blockIdx.x;
  int c = b % nj; b /= nj;
  int itile = b % NI; b /= NI;
  int n = b % B;
  int dir = b / B;

  const float2* __restrict__ Q = dir ? P2 : P1;  // queries
  const float2* __restrict__ D = dir ? P1 : P2;  // database

  // stage database chunk into LDS, pre-transformed
  const float2* dbase = D + n * N + c * jc;
  for (int t = threadIdx.x; t < jc; t += BLOCK) {
    float2 p = dbase[t];
    yb[t] = make_float4(-2.0f * p.x, -2.0f * p.y,
                        fmaf(p.x, p.x, p.y * p.y), 0.0f);
  }
  __syncthreads();

  // load TX queries into registers (coalesced)
  float qx[TX], qy[TX], m[TX];
  const float2* qbase = Q + n * N + itile * (BLOCK * TX) + threadIdx.x;
#pragma unroll
  for (int k = 0; k < TX; ++k) {
    float2 q = qbase[k * BLOCK];
    qx[k] = q.x; qy[k] = q.y;
    m[k] = INFINITY;
  }

  // main loop: wave-uniform LDS broadcast of db point, 3 ops per pair
#pragma unroll 4
  for (int j = 0; j < jc; ++j) {
    float4 y = yb[j];
#pragma unroll
    for (int k = 0; k < TX; ++k) {
      float t = fmaf(qx[k], y.x, fmaf(qy[k], y.y, y.z));
      m[k] = fminf(m[k], t);
    }
  }

  float* dst = partial + (((size_t)c * 2 + dir) * B + n) * N
             + itile * (BLOCK * TX) + threadIdx.x;
#pragma unroll
  for (int k = 0; k < TX; ++k) dst[k * BLOCK] = m[k];
}

// grid: 2*B*NT blocks; each block: one (dir, n, i-tile), 256 i's.
// min over c, add |q|^2, sqrt, block-sum -> bs[(dir*B+n)*NT + t]
__global__ __launch_bounds__(BLOCK) void chamfer_stage2(
    const float2* __restrict__ P1, const float2* __restrict__ P2,
    const float* __restrict__ partial, float* __restrict__ bs, int nj) {
  int b = blockIdx.x;
  int t = b % NT; b /= NT;
  int n = b % B;
  int dir = b / B;

  const float2* __restrict__ Q = dir ? P2 : P1;
  int i = t * BLOCK + threadIdx.x;

  float m = INFINITY;
  const float* __restrict__ pbase = partial + ((size_t)dir * B + n) * N + i;
#pragma unroll 4
  for (int c = 0; c < nj; ++c)
    m = fminf(m, pbase[(size_t)c * 2 * B * N]);

  float2 q = Q[n * N + i];
  float d2 = m + fmaf(q.x, q.x, q.y * q.y);
  float sum = sqrtf(fmaxf(d2, 0.0f));

  __shared__ float red[BLOCK];
  red[threadIdx.x] = sum;
  __syncthreads();
  for (int s = BLOCK / 2; s > 0; s >>= 1) {
    if (threadIdx.x < s) red[threadIdx.x] += red[threadIdx.x + s];
    __syncthreads();
  }
  if (threadIdx.x == 0) bs[(dir * B + n) * NT + t] = red[0];
}

// grid: B blocks x 64 threads; fixed-tree reduce of 2*NT=32 sums per n.
__global__ __launch_bounds__(64) void chamfer_stage3(
    const float* __restrict__ bs, float* __restrict__ out) {
  int n = blockIdx.x;
  int lane = threadIdx.x;
  float v = 0.0f;
  if (lane < 2 * NT) {
    int dir = lane / NT, t = lane % NT;
    v = bs[(dir * B + n) * NT + t];
  }
#pragma unroll
  for (int s = 32; s > 0; s >>= 1)
    v += __shfl_down(v, s, 64);
  if (lane == 0) out[n] = v * (0.5f / (float)N);
}

extern "C" void kernel_launch(void* const* d_in, const int* in_sizes, int n_in,
                              void* d_out, int out_size, void* d_ws, size_t ws_size,
                              hipStream_t stream) {
  const float2* P1 = (const float2*)d_in[0];
  const float2* P2 = (const float2*)d_in[1];
  float* out = (float*)d_out;
  float* partial = (float*)d_ws;

  // pick j-split so partials + blocksums fit in workspace
  size_t bs_bytes = 2 * B * NT * sizeof(float);
  int nj = 16;
  while (nj > 1 && (size_t)nj * 2 * B * N * sizeof(float) + bs_bytes > ws_size) nj >>= 1;
  int jc = N / nj;

  float* bs = partial + (size_t)nj * 2 * B * N;

  chamfer_stage1<<<dim3(2 * B * NI * nj), BLOCK, jc * sizeof(float4), stream>>>(
      P1, P2, partial, nj, jc);
  chamfer_stage2<<<dim3(2 * B * NT), BLOCK, 0, stream>>>(P1, P2, partial, bs, nj);
  chamfer_stage3<<<dim3(B), 64, 0, stream>>>(bs, out);
}